// Round 7
// baseline (212.725 us; speedup 1.0000x reference)
//
#include <hip/hip_runtime.h>
#include <hip/hip_bf16.h>

// Problem constants
#define LNUM 8
#define ENUM 8
#define DDIM 256
#define BSZ  16384
#define H1N  64
#define H2N  32

#define BT   64     // rows per block
#define NTHR 512    // 8 waves

#define PH1  72     // h1T row pitch (u16)
#define PH2  40     // h2T row pitch (u16)
#define PSW  9      // softmax pitch (floats)

// ws element offsets (u16) for fragment-ordered weights (frag = 1 KB linear)
#define WS1_OFF 0           // 64 steps * 16384
#define WS2_OFF 1048576     // 64 steps * 2048
#define WS3_OFF 1179648     // 64 steps * 8192   (R6 BUG: used 4096 stride)

// LDS arena offsets (u16). Total 68736 u16 = 137472 B.
#define W1A 0               // W1 buf0 (16384)
#define W1B 16384           // W1 buf1 (16384) -- doubles as x-exchange (XEX)
#define W2A 32768           // (2048)
#define W2B 34816           // (2048)
#define W3A 36864           // (8192)  <- was 4096: overflowed into W3B/H1T
#define W3B 45056           // (8192)
#define H1O 53248           // H1T[2] : 2 * 64*72 = 9216
#define H2O 62464           // H2T[2] : 2 * 64*40 = 5120
#define SWO 67584           // 64*9 floats = 1152 u16

typedef float f32x4 __attribute__((ext_vector_type(4)));
typedef unsigned short u16x8 __attribute__((ext_vector_type(8)));
typedef unsigned short u16x4 __attribute__((ext_vector_type(4)));
typedef __bf16 bf16x8 __attribute__((ext_vector_type(8)));

#define Z4 ((f32x4){0.f, 0.f, 0.f, 0.f})

// Round-to-nearest-even f32 -> bf16 (truncation bias compounds over 24 GEMMs).
static __device__ __forceinline__ unsigned short f2bf(float f) {
    unsigned u = __builtin_bit_cast(unsigned, f);
    u += 0x7fffu + ((u >> 16) & 1u);
    return (unsigned short)(u >> 16);
}

static __device__ __forceinline__ f32x4 mfma16(u16x8 a, u16x8 b, f32x4 c) {
    return __builtin_amdgcn_mfma_f32_16x16x32_bf16(
        __builtin_bit_cast(bf16x8, a), __builtin_bit_cast(bf16x8, b), c, 0, 0, 0);
}

// Async global->LDS DMA: 16 B/lane, lane i lands at ldsbase + i*16.
// Fragment (1 KB) == 64 lanes x 16 B contiguous -> one instruction per frag,
// zero VGPR round-trip, drained (for free) by the next __syncthreads.
static __device__ __forceinline__ void gl_lds(const unsigned short* g,
                                              unsigned short* l) {
    __builtin_amdgcn_global_load_lds(
        (const __attribute__((address_space(1))) unsigned int*)g,
        (__attribute__((address_space(3))) unsigned int*)l, 16, 0, 0);
}

// ---------------------------------------------------------------------------
// Kernel 1: fp32 weights -> bf16 B-fragment layout. COALESCED writes (thread
// = linear u16x8 of output), scattered 32 B reads (L2 absorbs).
// Fragment slot (q*16+r) holds W[n0+r][k0+q*8 .. +7].
// ---------------------------------------------------------------------------
__global__ __launch_bounds__(256) void cvt_w_frag(
    const float* __restrict__ w1, const float* __restrict__ w2,
    const float* __restrict__ w3, unsigned short* __restrict__ ws)
{
    int gid = blockIdx.x * 256 + threadIdx.x;
    const float* src;
    if (gid < 131072) {                          // W1: [s][n(64)][k(256)]
        int s = gid >> 11, o = gid & 2047;
        int f = o >> 6, lane = o & 63;
        int n = (f >> 3) * 16 + (lane & 15), k = (f & 7) * 32 + (lane >> 4) * 8;
        src = w1 + ((size_t)s * 16384 + n * 256 + k);
    } else if (gid < 147456) {                   // W2: [s][n(32)][k(64)]
        int g = gid - 131072;
        int s = g >> 8, o = g & 255;
        int f = o >> 6, lane = o & 63;
        int n = (f >> 1) * 16 + (lane & 15), k = (f & 1) * 32 + (lane >> 4) * 8;
        src = w2 + ((size_t)s * 2048 + n * 64 + k);
    } else {                                     // W3: [s][n(256)][k(32)]
        int g = gid - 147456;
        int s = g >> 10, o = g & 1023;
        int f = o >> 6, lane = o & 63;
        int n = f * 16 + (lane & 15), k = (lane >> 4) * 8;
        src = w3 + ((size_t)s * 8192 + n * 32 + k);
    }
    float4 a = *(const float4*)src;
    float4 b = *(const float4*)(src + 4);
    u16x8 p;
    p[0] = f2bf(a.x); p[1] = f2bf(a.y); p[2] = f2bf(a.z); p[3] = f2bf(a.w);
    p[4] = f2bf(b.x); p[5] = f2bf(b.y); p[6] = f2bf(b.z); p[7] = f2bf(b.w);
    *(u16x8*)(ws + (size_t)gid * 8) = p;         // coalesced
}

// ---------------------------------------------------------------------------
// Kernel 2: fused 8-layer x 8-expert MoE MLP.
// Weights staged one step ahead into double-buffered LDS via global_load_lds
// (fire-and-forget, no registers, drained by the pre-existing B1/B2 barriers
// long before use) -> L2 latency off the critical path.
// Buffer-safety: W1/W2(s+1) issued at top of step s (buffers last read in
// G1/G2(s-1); all waves provably past via B1(s-1)/B2(s-1)); W3(s+1) issued
// after B1(s) (buffer last read in G3(s-1), provably done at B1(s)).
// x lives in registers; layer transitions exchange x through the dead W1
// buffer with an XOR granule swizzle (conflict-free b128 reads).
// ---------------------------------------------------------------------------
__global__ __launch_bounds__(NTHR, 2) void moe_fused(
    const float* __restrict__ src, const unsigned short* __restrict__ Wf,
    const float* __restrict__ b1, const float* __restrict__ b2,
    const float* __restrict__ b3, const float* __restrict__ masks,
    float* __restrict__ out)
{
    __shared__ __align__(16) unsigned short AR[68736];   // 137472 B
    float* SW = (float*)&AR[SWO];

    const int tid  = threadIdx.x;
    const int lane = tid & 63;
    const int w    = tid >> 6;
    const int wm   = w >> 2;        // {0,1}
    const int wn   = w & 3;         // {0..3}
    const int n15  = lane & 15;
    const int q    = lane >> 4;
    const int b0   = blockIdx.x * BT;

    u16x8 xf[2][8];      // persistent x B-frags: rows wm*32+mt*16, K=256
    f32x4 ACC[2][4];     // output accumulator

    // ---- staging: one gl_lds per 1 KB fragment, spread across waves ----
    auto stage_w12 = [&](int ns, int nb) {
        const unsigned short* g1 = Wf + WS1_OFF + (size_t)ns * 16384 + lane * 8;
        unsigned short* l1 = AR + (nb ? W1B : W1A);
        #pragma unroll
        for (int i = 0; i < 4; ++i)
            gl_lds(g1 + (w * 4 + i) * 512, l1 + (w * 4 + i) * 512);
        if (w < 4) {
            const unsigned short* g2 = Wf + WS2_OFF + (size_t)ns * 2048 + lane * 8;
            gl_lds(g2 + w * 512, AR + (nb ? W2B : W2A) + w * 512);
        }
    };
    auto stage_w3 = [&](int ns, int nb) {       // 16 frags = 8192 u16 (full W3)
        const unsigned short* g3 = Wf + WS3_OFF + (size_t)ns * 8192 + lane * 8;
        unsigned short* l3 = AR + (nb ? W3B : W3A);
        #pragma unroll
        for (int i = 0; i < 2; ++i)
            gl_lds(g3 + (w * 2 + i) * 512, l3 + (w * 2 + i) * 512);
    };

    auto stage_softmax = [&](int l) {
        if (tid < 64) {
            const float* mp = masks + ((size_t)l * BSZ + b0 + tid) * ENUM;
            float4 m0 = *(const float4*)mp;
            float4 m1 = *(const float4*)(mp + 4);
            float mv[8] = {m0.x, m0.y, m0.z, m0.w, m1.x, m1.y, m1.z, m1.w};
            float mx = mv[0];
            #pragma unroll
            for (int e = 1; e < 8; ++e) mx = fmaxf(mx, mv[e]);
            float s = 0.f;
            #pragma unroll
            for (int e = 0; e < 8; ++e) { mv[e] = expf(mv[e] - mx); s += mv[e]; }
            float inv = 1.f / s;
            #pragma unroll
            for (int e = 0; e < 8; ++e) SW[tid * PSW + e] = mv[e] * inv;
        }
    };

    auto acc_init = [&](int l) {
        const float* b3l = b3 + (size_t)l * ENUM * DDIM;
        #pragma unroll
        for (int mt = 0; mt < 2; ++mt)
            #pragma unroll
            for (int nt = 0; nt < 4; ++nt) ACC[mt][nt] = Z4;
        #pragma unroll 2
        for (int e2 = 0; e2 < ENUM; ++e2) {
            float swv[2][4];
            #pragma unroll
            for (int mt = 0; mt < 2; ++mt)
                #pragma unroll
                for (int rg = 0; rg < 4; ++rg)
                    swv[mt][rg] = SW[(wm*32 + mt*16 + q*4 + rg) * PSW + e2];
            #pragma unroll
            for (int nt = 0; nt < 4; ++nt) {
                float bv = b3l[e2 * DDIM + wn*64 + nt*16 + n15];
                #pragma unroll
                for (int mt = 0; mt < 2; ++mt)
                    #pragma unroll
                    for (int rg = 0; rg < 4; ++rg)
                        ACC[mt][nt][rg] += swv[mt][rg] * bv;
            }
        }
    };

    // ---- x exchange in XEX (= W1 buf1), XOR granule swizzle, pitch 256 ----
    auto xf_read = [&]() {
        #pragma unroll
        for (int mt = 0; mt < 2; ++mt)
            #pragma unroll
            for (int kt = 0; kt < 8; ++kt) {
                int row  = wm*32 + mt*16 + n15;
                int phys = (kt*4 + q) ^ (row & 31);
                xf[mt][kt] = *(const u16x8*)&AR[W1B + row*256 + phys*8];
            }
    };
    auto x_write = [&]() {
        #pragma unroll
        for (int mt = 0; mt < 2; ++mt)
            #pragma unroll
            for (int nt = 0; nt < 4; ++nt)
                #pragma unroll
                for (int rg = 0; rg < 4; ++rg) {
                    int row  = wm*32 + mt*16 + q*4 + rg;
                    int col  = wn*64 + nt*16 + n15;
                    int phys = (col >> 3) ^ (row & 31);
                    AR[W1B + row*256 + phys*8 + (col & 7)] = f2bf(ACC[mt][nt][rg]);
                }
    };

    // ================= prologue =================
    stage_w12(0, 0);
    stage_w3(0, 0);
    #pragma unroll
    for (int i = 0; i < 4; ++i) {                // layer-0 x -> XEX (swizzled)
        int o = (i * NTHR + tid) * 8;
        int r = o >> 8, c = o & 255;
        const float* p = src + (size_t)(b0 + r) * DDIM + c;
        float4 f0 = *(const float4*)(p);
        float4 f1 = *(const float4*)(p + 4);
        u16x8 pk;
        pk[0] = f2bf(f0.x); pk[1] = f2bf(f0.y); pk[2] = f2bf(f0.z); pk[3] = f2bf(f0.w);
        pk[4] = f2bf(f1.x); pk[5] = f2bf(f1.y); pk[6] = f2bf(f1.z); pk[7] = f2bf(f1.w);
        int phys = (c >> 3) ^ (r & 31);
        *(u16x8*)&AR[W1B + r*256 + phys*8] = pk;
    }
    stage_softmax(0);
    __syncthreads();          // weights(0), x, SW all landed (vmcnt drained)
    xf_read();
    acc_init(0);
    __syncthreads();          // xf reads done before step 0 stages into W1B

    // ================= expert-step loop =================
    #pragma unroll 1
    for (int s = 0; s < LNUM * ENUM; ++s) {
        const int e = s & 7, l = s >> 3, pb = s & 1, nb = pb ^ 1;

        if (s < 63) stage_w12(s + 1, nb);        // fire-and-forget

        // ---- G1 (transposed): lane -> feats wn*16+q*4+rg, 4 MFMA chains ----
        u16x8 wf[8];
        {
            const unsigned short* w1l = AR + (pb ? W1B : W1A) + wn*4096 + lane*8;
            #pragma unroll
            for (int kt = 0; kt < 8; ++kt)
                wf[kt] = *(const u16x8*)(w1l + kt * 512);
        }
        f32x4 a1[2][2] = {{Z4, Z4}, {Z4, Z4}};
        #pragma unroll
        for (int kt = 0; kt < 4; ++kt) {
            a1[0][0] = mfma16(wf[kt],     xf[0][kt],     a1[0][0]);
            a1[1][0] = mfma16(wf[kt],     xf[1][kt],     a1[1][0]);
            a1[0][1] = mfma16(wf[kt + 4], xf[0][kt + 4], a1[0][1]);
            a1[1][1] = mfma16(wf[kt + 4], xf[1][kt + 4], a1[1][1]);
        }
        {
            float4 bb1 = *(const float4*)(b1 + s * 64 + wn * 16 + q * 4);
            unsigned short* h1w = AR + H1O + pb * 4608;
            #pragma unroll
            for (int mt = 0; mt < 2; ++mt) {
                u16x4 pk;
                #pragma unroll
                for (int rg = 0; rg < 4; ++rg)
                    pk[rg] = f2bf(fmaxf(a1[mt][0][rg] + a1[mt][1][rg] + bb1[rg], 0.f));
                *(u16x4*)(h1w + (wm*32 + mt*16 + n15) * PH1 + wn*16 + q*4) = pk;
            }
        }
        __syncthreads();                         // B1: h1 ready; W1/W2(s+1) drained

        if (s < 63) stage_w3(s + 1, nb);         // W3 buf provably dead here

        // ---- G2 (transposed): h2 feats wm*16+q*4+rg, row group wn ----
        f32x4 a2 = Z4;
        {
            const unsigned short* h1b = AR + H1O + pb * 4608;
            u16x8 h0 = *(const u16x8*)(h1b + (wn*16 + n15) * PH1 + q*8);
            u16x8 h1v = *(const u16x8*)(h1b + (wn*16 + n15) * PH1 + q*8 + 32);
            const unsigned short* w2l = AR + (pb ? W2B : W2A) + wm*1024 + lane*8;
            a2 = mfma16(*(const u16x8*)(w2l), h0, a2);
            a2 = mfma16(*(const u16x8*)(w2l + 512), h1v, a2);
        }
        {
            float4 bb2 = *(const float4*)(b2 + s * 32 + wm * 16 + q * 4);
            int row = wn*16 + n15;
            float sw = SW[row * PSW + e];
            u16x4 pk;
            #pragma unroll
            for (int rg = 0; rg < 4; ++rg)
                pk[rg] = f2bf(fmaxf(a2[rg] + bb2[rg], 0.f) * sw);
            *(u16x4*)(AR + H2O + pb*2560 + row * PH2 + wm*16 + q*4) = pk;
        }
        __syncthreads();                         // B2: h2 ready; W3(s+1) drained

        // ---- G3: ACC += h2 @ W3^T ----
        {
            const unsigned short* h2b = AR + H2O + pb * 2560;
            u16x8 g0 = *(const u16x8*)(h2b + (wm*32 + n15) * PH2 + q*8);
            u16x8 g1v = *(const u16x8*)(h2b + (wm*32 + 16 + n15) * PH2 + q*8);
            const unsigned short* w3l = AR + (pb ? W3B : W3A) + wn*2048 + lane*8;
            #pragma unroll
            for (int nt = 0; nt < 4; ++nt) {
                u16x8 wv = *(const u16x8*)(w3l + nt * 512);
                ACC[0][nt] = mfma16(g0, wv, ACC[0][nt]);
                ACC[1][nt] = mfma16(g1v, wv, ACC[1][nt]);
            }
        }

        // ---- layer transition (s odd -> XEX = W1 buf1 is the dead buffer) ----
        if (e == 7 && l < LNUM - 1) {
            x_write();
            __syncthreads();                     // T1: x visible
            xf_read();
            stage_softmax(l + 1);
            __syncthreads();                     // T2: xf reads done, SW ready
            acc_init(l + 1);
        }
    }

    // ================= final store (fp32) =================
    #pragma unroll
    for (int mt = 0; mt < 2; ++mt)
        #pragma unroll
        for (int nt = 0; nt < 4; ++nt)
            #pragma unroll
            for (int rg = 0; rg < 4; ++rg)
                out[(size_t)(b0 + wm*32 + mt*16 + q*4 + rg) * DDIM
                    + wn*64 + nt*16 + n15] = ACC[mt][nt][rg];
}

extern "C" void kernel_launch(void* const* d_in, const int* in_sizes, int n_in,
                              void* d_out, int out_size, void* d_ws, size_t ws_size,
                              hipStream_t stream) {
    const float* src   = (const float*)d_in[0];
    const float* W1    = (const float*)d_in[1];
    const float* b1    = (const float*)d_in[2];
    const float* W2    = (const float*)d_in[3];
    const float* b2    = (const float*)d_in[4];
    const float* W3    = (const float*)d_in[5];
    const float* b3    = (const float*)d_in[6];
    const float* masks = (const float*)d_in[7];
    float* out = (float*)d_out;
    unsigned short* ws = (unsigned short*)d_ws;   // needs 3,407,872 B

    hipLaunchKernelGGL(cvt_w_frag, dim3(832), dim3(256), 0, stream, W1, W2, W3, ws);
    hipLaunchKernelGGL(moe_fused, dim3(BSZ / BT), dim3(NTHR), 0, stream,
                       src, ws, b1, b2, b3, masks, out);
}